// Round 18
// baseline (535.712 us; speedup 1.0000x reference)
//
#include <hip/hip_runtime.h>

typedef unsigned short u16;
typedef unsigned char u8;
typedef unsigned int u32;
typedef __bf16 bf16x8 __attribute__((ext_vector_type(8)));
typedef float f32x4 __attribute__((ext_vector_type(4)));

constexpr int BATCH = 8;
constexpr int C = 256;
constexpr int H = 64;
constexpr int W = 64;
constexpr int HW = H * W;          // 4096
constexpr int HH = 62, WW = 62;    // valid patch grid
constexpr int NQ = HH * WW;        // 3844
constexpr int SEG = 4;             // y-steps per reduce block (was 8)
constexpr int NBLK_RED = 1008;     // sum over diagonals of ceil(len/4)

// ws layout (bytes). pval/pidx dedicated; 2 Q-slots rotate.
constexpr size_t OFF_RNORM = 0;
constexpr size_t OFF_RESV = 262144;
constexpr size_t OFF_RESI = 385280;
constexpr size_t OFF_PV = 508416;
constexpr size_t OFF_PI = OFF_PV + 62980096;
constexpr size_t OFF_SLOT0 = OFF_PI + 15745024;
constexpr size_t SP_H1 = 0;
constexpr size_t SP_L1 = 2097152;
constexpr size_t SP_H2 = 4194304;
constexpr size_t SP_L2 = 6291456;
constexpr size_t SP_Q = 8388608;
constexpr size_t SLOT_BYTES = 75513856;
constexpr size_t PVIMG = (size_t)NQ * 512;

// async global->LDS, 16B per lane
typedef const __attribute__((address_space(1))) unsigned int* gas_ptr;
typedef __attribute__((address_space(3))) unsigned int* las_ptr;
__device__ __forceinline__ void gl16(const void* g, void* l) {
  __builtin_amdgcn_global_load_lds((gas_ptr)g, (las_ptr)l, 16, 0, 0);
}

__device__ __forceinline__ int pre_of(int ki) {
  if (ki <= 62) return ki * (ki + 1) / 2;
  int r = 123 - ki;
  return 1953 + 1891 - r * (r + 1) / 2;
}

// ---------------------------------------------------------------------------
// norm: per-position reciprocal channel-L2 norm. rnorm[tensor][b][pos]
// ---------------------------------------------------------------------------
__global__ __launch_bounds__(256) void norm_kernel(const float* __restrict__ f1,
                                                   const float* __restrict__ f2,
                                                   float* __restrict__ rnorm) {
  int by = blockIdx.x;
  int tensor = blockIdx.y;
  const float* f = tensor ? f2 : f1;
  int b = by >> 6, y = by & 63;
  int x = threadIdx.x & 63;
  int cq = threadIdx.x >> 6;
  const float* base = f + ((size_t)b * C) * HW + y * W + x;
  float s = 0.f;
  for (int c = cq; c < C; c += 4) {
    float v = base[(size_t)c * HW];
    s = fmaf(v, v, s);
  }
  __shared__ float sm[4][64];
  sm[cq][x] = s;
  __syncthreads();
  if (threadIdx.x < 64) {
    float t = sm[0][x] + sm[1][x] + sm[2][x] + sm[3][x];
    float nrm = fmaxf(sqrtf(t), 1e-12f);
    rnorm[((size_t)tensor * BATCH + b) * HW + y * W + x] = 1.0f / nrm;
  }
}

// ---------------------------------------------------------------------------
// convert body: normalize + hi/lo bf16 split, [pos][c] planes. (proven)
// ---------------------------------------------------------------------------
__device__ __forceinline__ void convert_body(int chunk, int tensor, int bi,
                                             const float* __restrict__ f1,
                                             const float* __restrict__ f2,
                                             const float* __restrict__ rnorm,
                                             char* slot, char* smemraw, int t) {
  typedef u32 row_t[257];
  row_t* sm = (row_t*)smemraw;
  int pos0 = chunk * 32;
  const float* f = (tensor ? f2 : f1) + (size_t)bi * C * HW;
  const float* rn = rnorm + ((size_t)tensor * BATCH + bi) * HW + pos0;
  u16* dh = (u16*)(slot + (tensor ? SP_H2 : SP_H1)) + (size_t)pos0 * C;
  u16* dl = (u16*)(slot + (tensor ? SP_L2 : SP_L1)) + (size_t)pos0 * C;

  int px = t & 31, cg = t >> 5;
  float r = rn[px];
  for (int kk = 0; kk < 32; ++kk) {
    int c = (cg << 5) + kk;
    float v = f[(size_t)c * HW + pos0 + px] * r;
    __bf16 h = (__bf16)v;        // RNE
    float hf = (float)h;
    __bf16 lo = (__bf16)(v - hf);
    sm[px][c] = ((u32)__builtin_bit_cast(u16, h) << 16) | (u32)__builtin_bit_cast(u16, lo);
  }
  __syncthreads();
  int px2 = t >> 3, seg = t & 7;
  int c0 = seg * 32;
  for (int g8 = 0; g8 < 4; ++g8) {
    u32 hw0, hw1, hw2, hw3, lw0, lw1, lw2, lw3;
    u32 a, b2;
    a = sm[px2][c0 + g8 * 8 + 0]; b2 = sm[px2][c0 + g8 * 8 + 1];
    hw0 = (a >> 16) | (b2 & 0xFFFF0000u); lw0 = (a & 0xFFFFu) | (b2 << 16);
    a = sm[px2][c0 + g8 * 8 + 2]; b2 = sm[px2][c0 + g8 * 8 + 3];
    hw1 = (a >> 16) | (b2 & 0xFFFF0000u); lw1 = (a & 0xFFFFu) | (b2 << 16);
    a = sm[px2][c0 + g8 * 8 + 4]; b2 = sm[px2][c0 + g8 * 8 + 5];
    hw2 = (a >> 16) | (b2 & 0xFFFF0000u); lw2 = (a & 0xFFFFu) | (b2 << 16);
    a = sm[px2][c0 + g8 * 8 + 6]; b2 = sm[px2][c0 + g8 * 8 + 7];
    hw3 = (a >> 16) | (b2 & 0xFFFF0000u); lw3 = (a & 0xFFFFu) | (b2 << 16);
    size_t off = (size_t)px2 * C + c0 + g8 * 8;
    uint4 hv; hv.x = hw0; hv.y = hw1; hv.z = hw2; hv.w = hw3;
    uint4 lv; lv.x = lw0; lv.y = lw1; lv.z = lw2; lv.w = lw3;
    *(uint4*)(dh + off) = hv;
    *(uint4*)(dl + off) = lv;
  }
}

// ---------------------------------------------------------------------------
// pgemm body (champion, bit-exact): BK=32 dbuf 2-phase pipeline, parity
// swizzle, split-bf16 3-product MFMA, NT Q stores, 2D per-XCD tiling.
// ---------------------------------------------------------------------------
__device__ __forceinline__ void pgemm_body(int bid, char* slot, char* smem, int t) {
  const u16* hi1 = (const u16*)(slot + SP_H1);
  const u16* lo1 = (const u16*)(slot + SP_L1);
  const u16* hi2 = (const u16*)(slot + SP_H2);
  const u16* lo2 = (const u16*)(slot + SP_L2);
  float* P = (float*)(slot + SP_Q);

  // 2D XCD tiling: 8p x 16q rectangles per XCD (3MB operand footprint).
  int xcd = bid & 7, idx = bid >> 3;
  int p0 = (((xcd >> 1) * 8 + (idx >> 4)) << 7);
  int q0 = (((xcd & 1) * 16 + (idx & 15)) << 7);

  int l = t & 63, w = t >> 6, wm = w >> 1, wn = w & 1;
  int lr = l & 15, lh = l >> 4;

  const u16* srcs[4] = {hi1 + (size_t)p0 * 256, lo1 + (size_t)p0 * 256,
                        hi2 + (size_t)q0 * 256, lo2 + (size_t)q0 * 256};

  f32x4 acc[4][4];
#pragma unroll
  for (int mf = 0; mf < 4; ++mf)
#pragma unroll
    for (int nf = 0; nf < 4; ++nf)
      acc[mf][nf] = (f32x4){0.f, 0.f, 0.f, 0.f};

  auto stage = [&](int b, int kt) {
    char* base = smem + b * 32768;
#pragma unroll
    for (int pl = 0; pl < 4; ++pl) {
      const u16* s = srcs[pl];
#pragma unroll
      for (int wq = 0; wq < 2; ++wq) {
        int ci = (w * 2 + wq) * 64 + l;
        int row = ci >> 2, sl = ci & 3;
        int q = sl ^ ((row >> 1) & 3);
        size_t goff = (size_t)row * 256 + kt * 32 + (q << 3);
        gl16(s + goff, base + pl * 8192 + (w * 2 + wq) * 1024 + l * 16);
      }
    }
  };

  stage(0, 0);
  __syncthreads();

  for (int kt = 0; kt < 8; ++kt) {
    int b = kt & 1;
    if (kt < 7) stage(b ^ 1, kt + 1);
    char* sAh = smem + b * 32768;
    char* sAl = sAh + 8192;
    char* sBh = sAh + 16384;
    char* sBl = sAh + 24576;
    bf16x8 ah[4], al[4];
#pragma unroll
    for (int mf = 0; mf < 4; ++mf) {
      int row = wm * 64 + mf * 16 + lr;
      int off = row * 64 + ((lh ^ ((row >> 1) & 3)) << 4);
      ah[mf] = *(const bf16x8*)(sAh + off);
      al[mf] = *(const bf16x8*)(sAl + off);
    }
#pragma unroll
    for (int nf = 0; nf < 4; ++nf) {
      int row = wn * 64 + nf * 16 + lr;
      int off = row * 64 + ((lh ^ ((row >> 1) & 3)) << 4);
      bf16x8 bh = *(const bf16x8*)(sBh + off);
      bf16x8 bl = *(const bf16x8*)(sBl + off);
#pragma unroll
      for (int mf = 0; mf < 4; ++mf) {
        acc[mf][nf] = __builtin_amdgcn_mfma_f32_16x16x32_bf16(ah[mf], bh, acc[mf][nf], 0, 0, 0);
        acc[mf][nf] = __builtin_amdgcn_mfma_f32_16x16x32_bf16(al[mf], bh, acc[mf][nf], 0, 0, 0);
        acc[mf][nf] = __builtin_amdgcn_mfma_f32_16x16x32_bf16(ah[mf], bl, acc[mf][nf], 0, 0, 0);
      }
    }
    __syncthreads();
  }

  // Q epilogue: 2 passes x 2 planes; staged P quadrant [64][68] in LDS.
  float* sq = (float*)smem;
#pragma unroll
  for (int pass = 0; pass < 2; ++pass) {
    if (pass) __syncthreads();
    if (wn == pass) {
      float* buf = sq + wm * 4352;
#pragma unroll
      for (int mf = 0; mf < 4; ++mf)
#pragma unroll
        for (int nf = 0; nf < 4; ++nf)
#pragma unroll
          for (int j = 0; j < 4; ++j)
            buf[(mf * 16 + lh * 4 + j) * 68 + nf * 16 + lr] = acc[mf][nf][j];
      *(f32x4*)(buf + l * 68 + 64) = (f32x4){0.f, 0.f, 0.f, 0.f};
    }
    __syncthreads();
    int tid2 = t & 127, sel = t >> 7;
    int ax = tid2 & 63, halfj = tid2 >> 6;
    const float* S = sq + sel * 4352;
    int rr1 = ax + 1 > 63 ? 63 : ax + 1;
    int rr2 = ax + 2 > 63 ? 63 : ax + 2;
    const float* S0 = S + ax * 68;
    const float* S1 = S + rr1 * 68;
    const float* S2 = S + rr2 * 68;
    int planeIdx = (((p0 >> 6) + sel) << 6) + (q0 >> 6) + pass;
    float* Qp = P + (((size_t)planeIdx) << 12);
#pragma unroll
    for (int gi = 0; gi < 4; ++gi) {
      int g = halfj * 4 + gi;
      int c0 = g * 8;
      float r0[12], r1a[12], r2a[12];
#pragma unroll
      for (int u = 0; u < 3; ++u) {
        *(f32x4*)(r0 + u * 4) = *(const f32x4*)(S0 + c0 + u * 4);
        *(f32x4*)(r1a + u * 4) = *(const f32x4*)(S1 + c0 + u * 4);
        *(f32x4*)(r2a + u * 4) = *(const f32x4*)(S2 + c0 + u * 4);
      }
      f32x4 qv0, qv1;
#pragma unroll
      for (int e = 0; e < 4; ++e) qv0[e] = r0[e] + r1a[e + 1] + r2a[e + 2];
#pragma unroll
      for (int e = 0; e < 4; ++e) qv1[e] = r0[e + 4] + r1a[e + 5] + r2a[e + 6];
      float* Qg = Qp + g * 512 + (ax << 2);
      __builtin_nontemporal_store(qv0, (f32x4*)(Qg));
      __builtin_nontemporal_store(qv1, (f32x4*)(Qg + 256));
    }
  }
}

// ---------------------------------------------------------------------------
// reduce body (champion logic, SEG-agnostic): 256 threads, ww = w2 and w2+4;
// NT Q loads, 3-deep register-rolling prefetch.
// ---------------------------------------------------------------------------
__device__ __forceinline__ void reduce_body(int rid, const char* slot,
                                            float* pval8, u8* pidx8, int t) {
  const float* QT = (const float*)(slot + SP_Q);

  int bid = rid;
  int ki = 0;
  for (ki = 0; ki < 123; ++ki) {
    int d = ki - 61; if (d < 0) d = -d;
    int ns = (62 - d + SEG - 1) / SEG;
    if (bid < ns) break;
    bid -= ns;
  }
  int k = ki - 61;
  int ystart = k < 0 ? -k : 0;
  int yend = k > 0 ? 61 - k : 61;
  int y0 = ystart + bid * SEG;
  int y1 = y0 + SEG; if (y1 > yend + 1) y1 = yend + 1;
  int sid0 = pre_of(ki) + (y0 - ystart);
  int pmax = yend + 2;

  int w2 = t >> 6, l = t & 63;

  float A[16], B[16], P0[16], P1[16], P2[16];

  auto ld = [&](int p, float* D) {
    const float* gp = QT + (((size_t)((p << 6) + (p + k))) << 12) + (l << 2);
#pragma unroll
    for (int h = 0; h < 2; ++h) {
      const float* g2 = gp + ((w2 + h * 4) << 9);
      *(f32x4*)(D + h * 8) = __builtin_nontemporal_load((const f32x4*)g2);
      *(f32x4*)(D + h * 8 + 4) = __builtin_nontemporal_load((const f32x4*)(g2 + 256));
    }
  };

  auto candstep = [&](int y, const float* D0, const float* D1, const float* D2) {
#pragma unroll
    for (int h = 0; h < 2; ++h) {
      int ww = w2 + h * 4;
      float best = __uint_as_float(0xFF800000u);
      int bbb = 0;
#pragma unroll
      for (int s = 0; s < 8; ++s) {
        float c = D0[h * 8 + s] + D1[h * 8 + s] + D2[h * 8 + s];
        bool valid = (ww * 8 + s) <= 61;
        if (valid && c > best) { best = c; bbb = s; }  // ascending s
      }
      size_t o = (size_t)(sid0 + (y - y0)) * 512 + (ww << 6) + l;
      pval8[o] = best;
      pidx8[o] = (u8)bbb;
    }
  };

  ld(y0, A);
  ld(y0 + 1, B);
  ld(y0 + 2, P0);
  ld(y0 + 3 > pmax ? pmax : y0 + 3, P1);
  ld(y0 + 4 > pmax ? pmax : y0 + 4, P2);

  int y = y0;
  while (true) {
    candstep(y, A, B, P0);
#pragma unroll
    for (int s = 0; s < 16; ++s) { A[s] = B[s]; B[s] = P0[s]; }
    if (++y >= y1) break;
    ld(y + 4 > pmax ? pmax : y + 4, P0);
    candstep(y, A, B, P1);
#pragma unroll
    for (int s = 0; s < 16; ++s) { A[s] = B[s]; B[s] = P1[s]; }
    if (++y >= y1) break;
    ld(y + 4 > pmax ? pmax : y + 4, P1);
    candstep(y, A, B, P2);
#pragma unroll
    for (int s = 0; s < 16; ++s) { A[s] = B[s]; B[s] = P2[s]; }
    if (++y >= y1) break;
    ld(y + 4 > pmax ? pmax : y + 4, P2);
  }
}

// ---------------------------------------------------------------------------
// standalone convert (prologue C(0))
// ---------------------------------------------------------------------------
__global__ __launch_bounds__(256) void convert_kernel(const float* __restrict__ f1,
                                                      const float* __restrict__ f2,
                                                      const float* __restrict__ rnorm,
                                                      int bi, char* __restrict__ slot) {
  __shared__ __align__(16) char smem[33024];
  convert_body(blockIdx.x, blockIdx.y, bi, f1, f2, rnorm, slot, smem, threadIdx.x);
}

// ---------------------------------------------------------------------------
// merged phase kernel: role-striped 1:1 (even bx -> pgemm, odd -> reduce)
// zone A [0,2080); zone B [2080,2336): convert.
// ---------------------------------------------------------------------------
__global__ __launch_bounds__(256, 2) void merged_kernel(const float* __restrict__ f1,
                                                        const float* __restrict__ f2,
                                                        const float* __restrict__ rnorm,
                                                        char* __restrict__ ws,
                                                        int pg_img, int rd_img, int cv_img) {
  __shared__ __align__(16) char smem[65536];
  int bx = blockIdx.x, t = threadIdx.x;
  char* slot0 = ws + OFF_SLOT0;

  if (bx < 2080) {
    if ((bx & 1) == 0) {
      int pid = bx >> 1;
      if (pg_img >= 0 && pid < 1024)
        pgemm_body(pid, slot0 + (size_t)(pg_img & 1) * SLOT_BYTES, smem, t);
    } else {
      int rid = bx >> 1;
      if (rd_img >= 0 && rid < NBLK_RED) {
        float* pv = (float*)(ws + OFF_PV) + (size_t)rd_img * PVIMG;
        u8* pi = (u8*)(ws + OFF_PI) + (size_t)rd_img * PVIMG;
        reduce_body(rid, slot0 + (size_t)(rd_img & 1) * SLOT_BYTES, pv, pi, t);
      }
    }
  } else {
    int cid = bx - 2080;
    if (cv_img >= 0)
      convert_body(cid & 127, cid >> 7, cv_img, f1, f2, rnorm,
                   slot0 + (size_t)(cv_img & 1) * SLOT_BYTES, smem, t);
  }
}

// ---------------------------------------------------------------------------
// combine: scan (jy, w) with exact compares; decode bb via one pidx read.
// ---------------------------------------------------------------------------
__global__ __launch_bounds__(256) void combine_kernel(const char* __restrict__ ws,
                                                      float* __restrict__ resv,
                                                      int* __restrict__ residx) {
  int q = blockIdx.x * 256 + threadIdx.x;
  if (q >= NQ) return;
  int b = blockIdx.y;
  const float* pval8 = (const float*)(ws + OFF_PV) + (size_t)b * PVIMG;
  const u8* pidx8 = (const u8*)(ws + OFF_PI) + (size_t)b * PVIMG;
  int y = q / 62, ax = q - y * 62;
  float best = __uint_as_float(0xFF800000u);
  int bjy = 0, bw = 0;
  for (int jy = 0; jy < 62; ++jy) {
    int ki = 61 + jy - y;
    int sid = pre_of(ki) + (y < jy ? y : jy);
    const float* p = pval8 + (size_t)sid * 512 + ax;
#pragma unroll
    for (int ww = 0; ww < 8; ++ww) {
      float v = p[ww << 6];
      if (v > best) { best = v; bjy = jy; bw = ww; }
    }
  }
  int kib = 61 + bjy - y;
  int sidb = pre_of(kib) + (y < bjy ? y : bjy);
  int bb = pidx8[(size_t)sidb * 512 + (bw << 6) + ax];
  resv[(size_t)b * NQ + q] = best;
  residx[(size_t)b * NQ + q] = bjy * 62 + bw * 8 + bb;
}

// ---------------------------------------------------------------------------
// assemble: flow (B,64,64,2), offset (B,9,64,64,2), sim (B,1,64,64)
// ---------------------------------------------------------------------------
__global__ __launch_bounds__(256) void assemble_kernel(const float* __restrict__ res_val,
                                                       const int* __restrict__ res_idx,
                                                       float* __restrict__ out) {
  int gid = blockIdx.x * 256 + threadIdx.x;
  if (gid >= BATCH * HW) return;
  int b = gid >> 12;
  int y = (gid >> 6) & 63;
  int x = gid & 63;

  float* out_flow = out;
  float* out_off = out + (size_t)BATCH * HW * 2;
  float* out_sim = out + (size_t)BATCH * HW * 2 + (size_t)BATCH * 9 * HW * 2;

  auto flow_at = [&](int yy, int xx, float* fx, float* fy) {
    if (yy >= 0 && yy < HH && xx >= 0 && xx < WW) {
      int idx = res_idx[(size_t)b * NQ + yy * WW + xx];
      *fx = (float)(idx % WW - xx);
      *fy = (float)(idx / WW - yy);
    } else {
      *fx = 0.f;
      *fy = 0.f;
    }
  };

  float fx, fy;
  flow_at(y, x, &fx, &fy);
  size_t fo = ((size_t)b * HW + y * W + x) * 2;
  out_flow[fo + 0] = fx;
  out_flow[fo + 1] = fy;

#pragma unroll
  for (int sft = 0; sft < 9; ++sft) {
    int i = sft / 3, jj = sft % 3;
    float ox, oy;
    flow_at(y - i, x - jj, &ox, &oy);
    size_t o = (((size_t)b * 9 + sft) * HW + y * W + x) * 2;
    out_off[o + 0] = ox;
    out_off[o + 1] = oy;
  }

  float sim = 0.f;
  if (y >= 1 && y <= HH && x >= 1 && x <= WW) {
    float mv = res_val[(size_t)b * NQ + (y - 1) * WW + (x - 1)];
    sim = mv * (1.0f / ((3.0f + 1e-5f) * 3.0f));  // patch norms are exactly 3
  }
  out_sim[(size_t)b * HW + y * W + x] = sim;
}

// ---------------------------------------------------------------------------
extern "C" void kernel_launch(void* const* d_in, const int* in_sizes, int n_in,
                              void* d_out, int out_size, void* d_ws, size_t ws_size,
                              hipStream_t stream) {
  const float* f1 = (const float*)d_in[0];
  const float* f2 = (const float*)d_in[1];
  float* out = (float*)d_out;
  char* ws = (char*)d_ws;

  float* rnorm = (float*)(ws + OFF_RNORM);
  float* resv = (float*)(ws + OFF_RESV);
  int* residx = (int*)(ws + OFF_RESI);
  char* slot0 = ws + OFF_SLOT0;

  norm_kernel<<<dim3(BATCH * H, 2), 256, 0, stream>>>(f1, f2, rnorm);
  convert_kernel<<<dim3(128, 2), 256, 0, stream>>>(f1, f2, rnorm, 0, slot0);

  for (int i = 0; i < 8; ++i) {
    int cv = (i + 1 < 8) ? i + 1 : -1;
    merged_kernel<<<2336, 256, 0, stream>>>(f1, f2, rnorm, ws, i, i - 1, cv);
  }
  merged_kernel<<<2336, 256, 0, stream>>>(f1, f2, rnorm, ws, -1, 7, -1);

  combine_kernel<<<dim3(16, BATCH), 256, 0, stream>>>(ws, resv, residx);

  int total = BATCH * HW;
  assemble_kernel<<<(total + 255) / 256, 256, 0, stream>>>(resv, residx, out);
}

// Round 19
// 467.059 us; speedup vs baseline: 1.1470x; 1.1470x over previous
//
#include <hip/hip_runtime.h>

typedef unsigned short u16;
typedef unsigned char u8;
typedef unsigned int u32;
typedef __bf16 bf16x8 __attribute__((ext_vector_type(8)));
typedef float f32x4 __attribute__((ext_vector_type(4)));

constexpr int BATCH = 8;
constexpr int C = 256;
constexpr int H = 64;
constexpr int W = 64;
constexpr int HW = H * W;          // 4096
constexpr int HH = 62, WW = 62;    // valid patch grid
constexpr int NQ = HH * WW;        // 3844
constexpr int SEG = 8;             // champion value
constexpr int NBLK_RED = 536;

// ws layout (bytes). pval/pidx dedicated; 2 Q-slots rotate.
constexpr size_t OFF_RNORM = 0;
constexpr size_t OFF_RESV = 262144;
constexpr size_t OFF_RESI = 385280;
constexpr size_t OFF_PV = 508416;
constexpr size_t OFF_PI = OFF_PV + 62980096;
constexpr size_t OFF_SLOT0 = OFF_PI + 15745024;
constexpr size_t SP_H1 = 0;
constexpr size_t SP_L1 = 2097152;
constexpr size_t SP_H2 = 4194304;
constexpr size_t SP_L2 = 6291456;
constexpr size_t SP_Q = 8388608;
constexpr size_t SLOT_BYTES = 75513856;
constexpr size_t PVIMG = (size_t)NQ * 512;

// async global->LDS, 16B per lane
typedef const __attribute__((address_space(1))) unsigned int* gas_ptr;
typedef __attribute__((address_space(3))) unsigned int* las_ptr;
__device__ __forceinline__ void gl16(const void* g, void* l) {
  __builtin_amdgcn_global_load_lds((gas_ptr)g, (las_ptr)l, 16, 0, 0);
}

__device__ __forceinline__ int pre_of(int ki) {
  if (ki <= 62) return ki * (ki + 1) / 2;
  int r = 123 - ki;
  return 1953 + 1891 - r * (r + 1) / 2;
}

// ---------------------------------------------------------------------------
// norm: per-position reciprocal channel-L2 norm. rnorm[tensor][b][pos]
// ---------------------------------------------------------------------------
__global__ __launch_bounds__(256) void norm_kernel(const float* __restrict__ f1,
                                                   const float* __restrict__ f2,
                                                   float* __restrict__ rnorm) {
  int by = blockIdx.x;
  int tensor = blockIdx.y;
  const float* f = tensor ? f2 : f1;
  int b = by >> 6, y = by & 63;
  int x = threadIdx.x & 63;
  int cq = threadIdx.x >> 6;
  const float* base = f + ((size_t)b * C) * HW + y * W + x;
  float s = 0.f;
  for (int c = cq; c < C; c += 4) {
    float v = base[(size_t)c * HW];
    s = fmaf(v, v, s);
  }
  __shared__ float sm[4][64];
  sm[cq][x] = s;
  __syncthreads();
  if (threadIdx.x < 64) {
    float t = sm[0][x] + sm[1][x] + sm[2][x] + sm[3][x];
    float nrm = fmaxf(sqrtf(t), 1e-12f);
    rnorm[((size_t)tensor * BATCH + b) * HW + y * W + x] = 1.0f / nrm;
  }
}

// ---------------------------------------------------------------------------
// convert body: normalize + hi/lo bf16 split, [pos][c] planes. (proven)
// ---------------------------------------------------------------------------
__device__ __forceinline__ void convert_body(int chunk, int tensor, int bi,
                                             const float* __restrict__ f1,
                                             const float* __restrict__ f2,
                                             const float* __restrict__ rnorm,
                                             char* slot, char* smemraw, int t) {
  typedef u32 row_t[257];
  row_t* sm = (row_t*)smemraw;
  int pos0 = chunk * 32;
  const float* f = (tensor ? f2 : f1) + (size_t)bi * C * HW;
  const float* rn = rnorm + ((size_t)tensor * BATCH + bi) * HW + pos0;
  u16* dh = (u16*)(slot + (tensor ? SP_H2 : SP_H1)) + (size_t)pos0 * C;
  u16* dl = (u16*)(slot + (tensor ? SP_L2 : SP_L1)) + (size_t)pos0 * C;

  int px = t & 31, cg = t >> 5;
  float r = rn[px];
  for (int kk = 0; kk < 32; ++kk) {
    int c = (cg << 5) + kk;
    float v = f[(size_t)c * HW + pos0 + px] * r;
    __bf16 h = (__bf16)v;        // RNE
    float hf = (float)h;
    __bf16 lo = (__bf16)(v - hf);
    sm[px][c] = ((u32)__builtin_bit_cast(u16, h) << 16) | (u32)__builtin_bit_cast(u16, lo);
  }
  __syncthreads();
  int px2 = t >> 3, seg = t & 7;
  int c0 = seg * 32;
  for (int g8 = 0; g8 < 4; ++g8) {
    u32 hw0, hw1, hw2, hw3, lw0, lw1, lw2, lw3;
    u32 a, b2;
    a = sm[px2][c0 + g8 * 8 + 0]; b2 = sm[px2][c0 + g8 * 8 + 1];
    hw0 = (a >> 16) | (b2 & 0xFFFF0000u); lw0 = (a & 0xFFFFu) | (b2 << 16);
    a = sm[px2][c0 + g8 * 8 + 2]; b2 = sm[px2][c0 + g8 * 8 + 3];
    hw1 = (a >> 16) | (b2 & 0xFFFF0000u); lw1 = (a & 0xFFFFu) | (b2 << 16);
    a = sm[px2][c0 + g8 * 8 + 4]; b2 = sm[px2][c0 + g8 * 8 + 5];
    hw2 = (a >> 16) | (b2 & 0xFFFF0000u); lw2 = (a & 0xFFFFu) | (b2 << 16);
    a = sm[px2][c0 + g8 * 8 + 6]; b2 = sm[px2][c0 + g8 * 8 + 7];
    hw3 = (a >> 16) | (b2 & 0xFFFF0000u); lw3 = (a & 0xFFFFu) | (b2 << 16);
    size_t off = (size_t)px2 * C + c0 + g8 * 8;
    uint4 hv; hv.x = hw0; hv.y = hw1; hv.z = hw2; hv.w = hw3;
    uint4 lv; lv.x = lw0; lv.y = lw1; lv.z = lw2; lv.w = lw3;
    *(uint4*)(dh + off) = hv;
    *(uint4*)(dl + off) = lv;
  }
}

// ---------------------------------------------------------------------------
// pgemm body: BK=32 dbuf, COUNTED-VMCNT 2-deep pipeline (T3/T4): stage(kt+2)
// loads stay in flight across MFMA(kt+1); per tile one read-done barrier +
// one counted-wait barrier (never vmcnt(0) mid-loop). Parity swizzle,
// split-bf16 3-product MFMA (bit-exact), NT Q stores, 2D per-XCD tiling.
// ---------------------------------------------------------------------------
__device__ __forceinline__ void pgemm_body(int bid, char* slot, char* smem, int t) {
  const u16* hi1 = (const u16*)(slot + SP_H1);
  const u16* lo1 = (const u16*)(slot + SP_L1);
  const u16* hi2 = (const u16*)(slot + SP_H2);
  const u16* lo2 = (const u16*)(slot + SP_L2);
  float* P = (float*)(slot + SP_Q);

  // 2D XCD tiling: 8p x 16q rectangles per XCD (3MB operand footprint).
  int xcd = bid & 7, idx = bid >> 3;
  int p0 = (((xcd >> 1) * 8 + (idx >> 4)) << 7);
  int q0 = (((xcd & 1) * 16 + (idx & 15)) << 7);

  int l = t & 63, w = t >> 6, wm = w >> 1, wn = w & 1;
  int lr = l & 15, lh = l >> 4;

  const u16* srcs[4] = {hi1 + (size_t)p0 * 256, lo1 + (size_t)p0 * 256,
                        hi2 + (size_t)q0 * 256, lo2 + (size_t)q0 * 256};

  f32x4 acc[4][4];
#pragma unroll
  for (int mf = 0; mf < 4; ++mf)
#pragma unroll
    for (int nf = 0; nf < 4; ++nf)
      acc[mf][nf] = (f32x4){0.f, 0.f, 0.f, 0.f};

  auto stage = [&](int b, int kt) {
    char* base = smem + b * 32768;
#pragma unroll
    for (int pl = 0; pl < 4; ++pl) {
      const u16* s = srcs[pl];
#pragma unroll
      for (int wq = 0; wq < 2; ++wq) {
        int ci = (w * 2 + wq) * 64 + l;
        int row = ci >> 2, sl = ci & 3;
        int q = sl ^ ((row >> 1) & 3);
        size_t goff = (size_t)row * 256 + kt * 32 + (q << 3);
        gl16(s + goff, base + pl * 8192 + (w * 2 + wq) * 1024 + l * 16);
      }
    }
  };

  // prologue: tiles 0 and 1 in flight (8 loads/thread each)
  stage(0, 0);
  stage(1, 1);
  asm volatile("s_waitcnt vmcnt(8)" ::: "memory");   // tile 0 landed
  __builtin_amdgcn_sched_barrier(0);
  __builtin_amdgcn_s_barrier();
  __builtin_amdgcn_sched_barrier(0);

#pragma unroll
  for (int kt = 0; kt < 8; ++kt) {
    int b = kt & 1;
    char* sAh = smem + b * 32768;
    char* sAl = sAh + 8192;
    char* sBh = sAh + 16384;
    char* sBl = sAh + 24576;
    bf16x8 ah[4], al[4];
#pragma unroll
    for (int mf = 0; mf < 4; ++mf) {
      int row = wm * 64 + mf * 16 + lr;
      int off = row * 64 + ((lh ^ ((row >> 1) & 3)) << 4);
      ah[mf] = *(const bf16x8*)(sAh + off);
      al[mf] = *(const bf16x8*)(sAl + off);
    }
#pragma unroll
    for (int nf = 0; nf < 4; ++nf) {
      int row = wn * 64 + nf * 16 + lr;
      int off = row * 64 + ((lh ^ ((row >> 1) & 3)) << 4);
      bf16x8 bh = *(const bf16x8*)(sBh + off);
      bf16x8 bl = *(const bf16x8*)(sBl + off);
#pragma unroll
      for (int mf = 0; mf < 4; ++mf) {
        acc[mf][nf] = __builtin_amdgcn_mfma_f32_16x16x32_bf16(ah[mf], bh, acc[mf][nf], 0, 0, 0);
        acc[mf][nf] = __builtin_amdgcn_mfma_f32_16x16x32_bf16(al[mf], bh, acc[mf][nf], 0, 0, 0);
        acc[mf][nf] = __builtin_amdgcn_mfma_f32_16x16x32_bf16(ah[mf], bl, acc[mf][nf], 0, 0, 0);
      }
    }
    if (kt == 7) break;
    // readers of buf b done -> safe to refill it with tile kt+2
    __builtin_amdgcn_sched_barrier(0);
    __builtin_amdgcn_s_barrier();
    __builtin_amdgcn_sched_barrier(0);
    if (kt < 6) {
      stage(b, kt + 2);
      asm volatile("s_waitcnt vmcnt(8)" ::: "memory");  // tile kt+1 landed
    } else {
      asm volatile("s_waitcnt vmcnt(0)" ::: "memory");  // tile 7 landed
    }
    __builtin_amdgcn_sched_barrier(0);
    __builtin_amdgcn_s_barrier();
    __builtin_amdgcn_sched_barrier(0);
  }
  __syncthreads();   // MFMA(7) reads done before epilogue overwrites smem

  // Q epilogue: 2 passes x 2 planes; staged P quadrant [64][68] in LDS.
  float* sq = (float*)smem;
#pragma unroll
  for (int pass = 0; pass < 2; ++pass) {
    if (pass) __syncthreads();
    if (wn == pass) {
      float* buf = sq + wm * 4352;
#pragma unroll
      for (int mf = 0; mf < 4; ++mf)
#pragma unroll
        for (int nf = 0; nf < 4; ++nf)
#pragma unroll
          for (int j = 0; j < 4; ++j)
            buf[(mf * 16 + lh * 4 + j) * 68 + nf * 16 + lr] = acc[mf][nf][j];
      *(f32x4*)(buf + l * 68 + 64) = (f32x4){0.f, 0.f, 0.f, 0.f};
    }
    __syncthreads();
    int tid2 = t & 127, sel = t >> 7;
    int ax = tid2 & 63, halfj = tid2 >> 6;
    const float* S = sq + sel * 4352;
    int rr1 = ax + 1 > 63 ? 63 : ax + 1;
    int rr2 = ax + 2 > 63 ? 63 : ax + 2;
    const float* S0 = S + ax * 68;
    const float* S1 = S + rr1 * 68;
    const float* S2 = S + rr2 * 68;
    int planeIdx = (((p0 >> 6) + sel) << 6) + (q0 >> 6) + pass;
    float* Qp = P + (((size_t)planeIdx) << 12);
#pragma unroll
    for (int gi = 0; gi < 4; ++gi) {
      int g = halfj * 4 + gi;
      int c0 = g * 8;
      float r0[12], r1a[12], r2a[12];
#pragma unroll
      for (int u = 0; u < 3; ++u) {
        *(f32x4*)(r0 + u * 4) = *(const f32x4*)(S0 + c0 + u * 4);
        *(f32x4*)(r1a + u * 4) = *(const f32x4*)(S1 + c0 + u * 4);
        *(f32x4*)(r2a + u * 4) = *(const f32x4*)(S2 + c0 + u * 4);
      }
      f32x4 qv0, qv1;
#pragma unroll
      for (int e = 0; e < 4; ++e) qv0[e] = r0[e] + r1a[e + 1] + r2a[e + 2];
#pragma unroll
      for (int e = 0; e < 4; ++e) qv1[e] = r0[e + 4] + r1a[e + 5] + r2a[e + 6];
      float* Qg = Qp + g * 512 + (ax << 2);
      __builtin_nontemporal_store(qv0, (f32x4*)(Qg));
      __builtin_nontemporal_store(qv1, (f32x4*)(Qg + 256));
    }
  }
}

// ---------------------------------------------------------------------------
// reduce body (champion): 256 threads, ww = w2 and w2+4; NT Q loads.
// ---------------------------------------------------------------------------
__device__ __forceinline__ void reduce_body(int rid, const char* slot,
                                            float* pval8, u8* pidx8, int t) {
  const float* QT = (const float*)(slot + SP_Q);

  int bid = rid;
  int ki = 0;
  for (ki = 0; ki < 123; ++ki) {
    int d = ki - 61; if (d < 0) d = -d;
    int ns = (62 - d + SEG - 1) / SEG;
    if (bid < ns) break;
    bid -= ns;
  }
  int k = ki - 61;
  int ystart = k < 0 ? -k : 0;
  int yend = k > 0 ? 61 - k : 61;
  int y0 = ystart + bid * SEG;
  int y1 = y0 + SEG; if (y1 > yend + 1) y1 = yend + 1;
  int sid0 = pre_of(ki) + (y0 - ystart);
  int pmax = yend + 2;

  int w2 = t >> 6, l = t & 63;

  float A[16], B[16], P0[16], P1[16], P2[16];

  auto ld = [&](int p, float* D) {
    const float* gp = QT + (((size_t)((p << 6) + (p + k))) << 12) + (l << 2);
#pragma unroll
    for (int h = 0; h < 2; ++h) {
      const float* g2 = gp + ((w2 + h * 4) << 9);
      *(f32x4*)(D + h * 8) = __builtin_nontemporal_load((const f32x4*)g2);
      *(f32x4*)(D + h * 8 + 4) = __builtin_nontemporal_load((const f32x4*)(g2 + 256));
    }
  };

  auto candstep = [&](int y, const float* D0, const float* D1, const float* D2) {
#pragma unroll
    for (int h = 0; h < 2; ++h) {
      int ww = w2 + h * 4;
      float best = __uint_as_float(0xFF800000u);
      int bbb = 0;
#pragma unroll
      for (int s = 0; s < 8; ++s) {
        float c = D0[h * 8 + s] + D1[h * 8 + s] + D2[h * 8 + s];
        bool valid = (ww * 8 + s) <= 61;
        if (valid && c > best) { best = c; bbb = s; }  // ascending s
      }
      size_t o = (size_t)(sid0 + (y - y0)) * 512 + (ww << 6) + l;
      pval8[o] = best;
      pidx8[o] = (u8)bbb;
    }
  };

  ld(y0, A);
  ld(y0 + 1, B);
  ld(y0 + 2, P0);
  ld(y0 + 3 > pmax ? pmax : y0 + 3, P1);
  ld(y0 + 4 > pmax ? pmax : y0 + 4, P2);

  int y = y0;
  while (true) {
    candstep(y, A, B, P0);
#pragma unroll
    for (int s = 0; s < 16; ++s) { A[s] = B[s]; B[s] = P0[s]; }
    if (++y >= y1) break;
    ld(y + 4 > pmax ? pmax : y + 4, P0);
    candstep(y, A, B, P1);
#pragma unroll
    for (int s = 0; s < 16; ++s) { A[s] = B[s]; B[s] = P1[s]; }
    if (++y >= y1) break;
    ld(y + 4 > pmax ? pmax : y + 4, P1);
    candstep(y, A, B, P2);
#pragma unroll
    for (int s = 0; s < 16; ++s) { A[s] = B[s]; B[s] = P2[s]; }
    if (++y >= y1) break;
    ld(y + 4 > pmax ? pmax : y + 4, P2);
  }
}

// ---------------------------------------------------------------------------
// standalone convert (prologue C(0))
// ---------------------------------------------------------------------------
__global__ __launch_bounds__(256) void convert_kernel(const float* __restrict__ f1,
                                                      const float* __restrict__ f2,
                                                      const float* __restrict__ rnorm,
                                                      int bi, char* __restrict__ slot) {
  __shared__ __align__(16) char smem[33024];
  convert_body(blockIdx.x, blockIdx.y, bi, f1, f2, rnorm, slot, smem, threadIdx.x);
}

// ---------------------------------------------------------------------------
// merged phase kernel: role-striped blocks (2:1 pgemm:reduce + convert tail)
// ---------------------------------------------------------------------------
__global__ __launch_bounds__(256, 2) void merged_kernel(const float* __restrict__ f1,
                                                        const float* __restrict__ f2,
                                                        const float* __restrict__ rnorm,
                                                        char* __restrict__ ws,
                                                        int pg_img, int rd_img, int cv_img) {
  __shared__ __align__(16) char smem[65536];
  int bx = blockIdx.x, t = threadIdx.x;
  char* slot0 = ws + OFF_SLOT0;

  if (bx < 1608) {
    int m = bx % 3;
    if (m < 2) {
      int pid = (bx / 3) * 2 + m;
      if (pg_img >= 0 && pid < 1024)
        pgemm_body(pid, slot0 + (size_t)(pg_img & 1) * SLOT_BYTES, smem, t);
    } else {
      int rid = bx / 3;
      if (rd_img >= 0) {
        float* pv = (float*)(ws + OFF_PV) + (size_t)rd_img * PVIMG;
        u8* pi = (u8*)(ws + OFF_PI) + (size_t)rd_img * PVIMG;
        reduce_body(rid, slot0 + (size_t)(rd_img & 1) * SLOT_BYTES, pv, pi, t);
      }
    }
  } else {
    int cid = bx - 1608;
    if (cv_img >= 0)
      convert_body(cid & 127, cid >> 7, cv_img, f1, f2, rnorm,
                   slot0 + (size_t)(cv_img & 1) * SLOT_BYTES, smem, t);
  }
}

// ---------------------------------------------------------------------------
// combine: scan (jy, w) with exact compares; decode bb via one pidx read.
// ---------------------------------------------------------------------------
__global__ __launch_bounds__(256) void combine_kernel(const char* __restrict__ ws,
                                                      float* __restrict__ resv,
                                                      int* __restrict__ residx) {
  int q = blockIdx.x * 256 + threadIdx.x;
  if (q >= NQ) return;
  int b = blockIdx.y;
  const float* pval8 = (const float*)(ws + OFF_PV) + (size_t)b * PVIMG;
  const u8* pidx8 = (const u8*)(ws + OFF_PI) + (size_t)b * PVIMG;
  int y = q / 62, ax = q - y * 62;
  float best = __uint_as_float(0xFF800000u);
  int bjy = 0, bw = 0;
  for (int jy = 0; jy < 62; ++jy) {
    int ki = 61 + jy - y;
    int sid = pre_of(ki) + (y < jy ? y : jy);
    const float* p = pval8 + (size_t)sid * 512 + ax;
#pragma unroll
    for (int ww = 0; ww < 8; ++ww) {
      float v = p[ww << 6];
      if (v > best) { best = v; bjy = jy; bw = ww; }
    }
  }
  int kib = 61 + bjy - y;
  int sidb = pre_of(kib) + (y < bjy ? y : bjy);
  int bb = pidx8[(size_t)sidb * 512 + (bw << 6) + ax];
  resv[(size_t)b * NQ + q] = best;
  residx[(size_t)b * NQ + q] = bjy * 62 + bw * 8 + bb;
}

// ---------------------------------------------------------------------------
// assemble: flow (B,64,64,2), offset (B,9,64,64,2), sim (B,1,64,64)
// ---------------------------------------------------------------------------
__global__ __launch_bounds__(256) void assemble_kernel(const float* __restrict__ res_val,
                                                       const int* __restrict__ res_idx,
                                                       float* __restrict__ out) {
  int gid = blockIdx.x * 256 + threadIdx.x;
  if (gid >= BATCH * HW) return;
  int b = gid >> 12;
  int y = (gid >> 6) & 63;
  int x = gid & 63;

  float* out_flow = out;
  float* out_off = out + (size_t)BATCH * HW * 2;
  float* out_sim = out + (size_t)BATCH * HW * 2 + (size_t)BATCH * 9 * HW * 2;

  auto flow_at = [&](int yy, int xx, float* fx, float* fy) {
    if (yy >= 0 && yy < HH && xx >= 0 && xx < WW) {
      int idx = res_idx[(size_t)b * NQ + yy * WW + xx];
      *fx = (float)(idx % WW - xx);
      *fy = (float)(idx / WW - yy);
    } else {
      *fx = 0.f;
      *fy = 0.f;
    }
  };

  float fx, fy;
  flow_at(y, x, &fx, &fy);
  size_t fo = ((size_t)b * HW + y * W + x) * 2;
  out_flow[fo + 0] = fx;
  out_flow[fo + 1] = fy;

#pragma unroll
  for (int sft = 0; sft < 9; ++sft) {
    int i = sft / 3, jj = sft % 3;
    float ox, oy;
    flow_at(y - i, x - jj, &ox, &oy);
    size_t o = (((size_t)b * 9 + sft) * HW + y * W + x) * 2;
    out_off[o + 0] = ox;
    out_off[o + 1] = oy;
  }

  float sim = 0.f;
  if (y >= 1 && y <= HH && x >= 1 && x <= WW) {
    float mv = res_val[(size_t)b * NQ + (y - 1) * WW + (x - 1)];
    sim = mv * (1.0f / ((3.0f + 1e-5f) * 3.0f));  // patch norms are exactly 3
  }
  out_sim[(size_t)b * HW + y * W + x] = sim;
}

// ---------------------------------------------------------------------------
extern "C" void kernel_launch(void* const* d_in, const int* in_sizes, int n_in,
                              void* d_out, int out_size, void* d_ws, size_t ws_size,
                              hipStream_t stream) {
  const float* f1 = (const float*)d_in[0];
  const float* f2 = (const float*)d_in[1];
  float* out = (float*)d_out;
  char* ws = (char*)d_ws;

  float* rnorm = (float*)(ws + OFF_RNORM);
  float* resv = (float*)(ws + OFF_RESV);
  int* residx = (int*)(ws + OFF_RESI);
  char* slot0 = ws + OFF_SLOT0;

  norm_kernel<<<dim3(BATCH * H, 2), 256, 0, stream>>>(f1, f2, rnorm);
  convert_kernel<<<dim3(128, 2), 256, 0, stream>>>(f1, f2, rnorm, 0, slot0);

  for (int i = 0; i < 8; ++i) {
    int cv = (i + 1 < 8) ? i + 1 : -1;
    merged_kernel<<<1864, 256, 0, stream>>>(f1, f2, rnorm, ws, i, i - 1, cv);
  }
  merged_kernel<<<1864, 256, 0, stream>>>(f1, f2, rnorm, ws, -1, 7, -1);

  combine_kernel<<<dim3(16, BATCH), 256, 0, stream>>>(ws, resv, residx);

  int total = BATCH * HW;
  assemble_kernel<<<(total + 255) / 256, 256, 0, stream>>>(resv, residx, out);
}

// Round 20
// 451.202 us; speedup vs baseline: 1.1873x; 1.0351x over previous
//
#include <hip/hip_runtime.h>

typedef unsigned short u16;
typedef unsigned char u8;
typedef unsigned int u32;
typedef __bf16 bf16x8 __attribute__((ext_vector_type(8)));
typedef float f32x4 __attribute__((ext_vector_type(4)));

constexpr int BATCH = 8;
constexpr int C = 256;
constexpr int H = 64;
constexpr int W = 64;
constexpr int HW = H * W;          // 4096
constexpr int HH = 62, WW = 62;    // valid patch grid
constexpr int NQ = HH * WW;        // 3844
constexpr int SEG = 8;
constexpr int NBLK_RED = 536;

// ws layout (bytes). pval/pidx dedicated; 2 Q-slots rotate.
constexpr size_t OFF_RNORM = 0;
constexpr size_t OFF_RESV = 262144;
constexpr size_t OFF_RESI = 385280;
constexpr size_t OFF_PV = 508416;
constexpr size_t OFF_PI = OFF_PV + 62980096;
constexpr size_t OFF_SLOT0 = OFF_PI + 15745024;
constexpr size_t SP_H1 = 0;
constexpr size_t SP_L1 = 2097152;
constexpr size_t SP_H2 = 4194304;
constexpr size_t SP_L2 = 6291456;
constexpr size_t SP_Q = 8388608;
constexpr size_t SLOT_BYTES = 75513856;
constexpr size_t PVIMG = (size_t)NQ * 512;

// async global->LDS, 16B per lane
typedef const __attribute__((address_space(1))) unsigned int* gas_ptr;
typedef __attribute__((address_space(3))) unsigned int* las_ptr;
__device__ __forceinline__ void gl16(const void* g, void* l) {
  __builtin_amdgcn_global_load_lds((gas_ptr)g, (las_ptr)l, 16, 0, 0);
}

__device__ __forceinline__ int pre_of(int ki) {
  if (ki <= 62) return ki * (ki + 1) / 2;
  int r = 123 - ki;
  return 1953 + 1891 - r * (r + 1) / 2;
}

// ---------------------------------------------------------------------------
// norm: per-position reciprocal channel-L2 norm. rnorm[tensor][b][pos]
// ---------------------------------------------------------------------------
__global__ __launch_bounds__(256) void norm_kernel(const float* __restrict__ f1,
                                                   const float* __restrict__ f2,
                                                   float* __restrict__ rnorm) {
  int by = blockIdx.x;
  int tensor = blockIdx.y;
  const float* f = tensor ? f2 : f1;
  int b = by >> 6, y = by & 63;
  int x = threadIdx.x & 63;
  int cq = threadIdx.x >> 6;
  const float* base = f + ((size_t)b * C) * HW + y * W + x;
  float s = 0.f;
  for (int c = cq; c < C; c += 4) {
    float v = base[(size_t)c * HW];
    s = fmaf(v, v, s);
  }
  __shared__ float sm[4][64];
  sm[cq][x] = s;
  __syncthreads();
  if (threadIdx.x < 64) {
    float t = sm[0][x] + sm[1][x] + sm[2][x] + sm[3][x];
    float nrm = fmaxf(sqrtf(t), 1e-12f);
    rnorm[((size_t)tensor * BATCH + b) * HW + y * W + x] = 1.0f / nrm;
  }
}

// ---------------------------------------------------------------------------
// convert body (512 threads): normalize + hi/lo bf16 split, [pos][c] planes.
// Same per-element ops as proven 256-thread version; re-indexed.
// ---------------------------------------------------------------------------
__device__ __forceinline__ void convert_body(int chunk, int tensor, int bi,
                                             const float* __restrict__ f1,
                                             const float* __restrict__ f2,
                                             const float* __restrict__ rnorm,
                                             char* slot, char* smemraw, int t) {
  typedef u32 row_t[257];
  row_t* sm = (row_t*)smemraw;
  int pos0 = chunk * 32;
  const float* f = (tensor ? f2 : f1) + (size_t)bi * C * HW;
  const float* rn = rnorm + ((size_t)tensor * BATCH + bi) * HW + pos0;
  u16* dh = (u16*)(slot + (tensor ? SP_H2 : SP_H1)) + (size_t)pos0 * C;
  u16* dl = (u16*)(slot + (tensor ? SP_L2 : SP_L1)) + (size_t)pos0 * C;

  int px = t & 31, cg = t >> 5;      // cg 0..15
  float r = rn[px];
  for (int kk = 0; kk < 16; ++kk) {
    int c = (cg << 4) + kk;
    float v = f[(size_t)c * HW + pos0 + px] * r;
    __bf16 h = (__bf16)v;        // RNE
    float hf = (float)h;
    __bf16 lo = (__bf16)(v - hf);
    sm[px][c] = ((u32)__builtin_bit_cast(u16, h) << 16) | (u32)__builtin_bit_cast(u16, lo);
  }
  __syncthreads();
  int px2 = t >> 4, seg = t & 15;    // px2 0..31, seg 0..15
  int c0 = seg * 16;
  for (int g8 = 0; g8 < 2; ++g8) {
    u32 hw0, hw1, hw2, hw3, lw0, lw1, lw2, lw3;
    u32 a, b2;
    a = sm[px2][c0 + g8 * 8 + 0]; b2 = sm[px2][c0 + g8 * 8 + 1];
    hw0 = (a >> 16) | (b2 & 0xFFFF0000u); lw0 = (a & 0xFFFFu) | (b2 << 16);
    a = sm[px2][c0 + g8 * 8 + 2]; b2 = sm[px2][c0 + g8 * 8 + 3];
    hw1 = (a >> 16) | (b2 & 0xFFFF0000u); lw1 = (a & 0xFFFFu) | (b2 << 16);
    a = sm[px2][c0 + g8 * 8 + 4]; b2 = sm[px2][c0 + g8 * 8 + 5];
    hw2 = (a >> 16) | (b2 & 0xFFFF0000u); lw2 = (a & 0xFFFFu) | (b2 << 16);
    a = sm[px2][c0 + g8 * 8 + 6]; b2 = sm[px2][c0 + g8 * 8 + 7];
    hw3 = (a >> 16) | (b2 & 0xFFFF0000u); lw3 = (a & 0xFFFFu) | (b2 << 16);
    size_t off = (size_t)px2 * C + c0 + g8 * 8;
    uint4 hv; hv.x = hw0; hv.y = hw1; hv.z = hw2; hv.w = hw3;
    uint4 lv; lv.x = lw0; lv.y = lw1; lv.z = lw2; lv.w = lw3;
    *(uint4*)(dh + off) = hv;
    *(uint4*)(dl + off) = lv;
  }
}

// ---------------------------------------------------------------------------
// pgemm body (512 threads, 8 waves): each wave owns a 64x32 sub-tile
// (wm = w&1 row-half, wq4 = w>>1 col-quarter; acc[4][2]). BK=32 dbuf with
// counted-vmcnt 2-deep pipeline (4 loads/thread/tile -> vmcnt(4)). Parity
// swizzle, split-bf16 3-product MFMA (per-output K order unchanged ->
// bit-exact), NT Q stores, 2D per-XCD tiling.
// ---------------------------------------------------------------------------
__device__ __forceinline__ void pgemm_body(int bid, char* slot, char* smem, int t) {
  const u16* hi1 = (const u16*)(slot + SP_H1);
  const u16* lo1 = (const u16*)(slot + SP_L1);
  const u16* hi2 = (const u16*)(slot + SP_H2);
  const u16* lo2 = (const u16*)(slot + SP_L2);
  float* P = (float*)(slot + SP_Q);

  int xcd = bid & 7, idx = bid >> 3;
  int p0 = (((xcd >> 1) * 8 + (idx >> 4)) << 7);
  int q0 = (((xcd & 1) * 16 + (idx & 15)) << 7);

  int l = t & 63, w = t >> 6;
  int wm = w & 1, wq4 = w >> 1;
  int lr = l & 15, lh = l >> 4;

  const u16* srcs[4] = {hi1 + (size_t)p0 * 256, lo1 + (size_t)p0 * 256,
                        hi2 + (size_t)q0 * 256, lo2 + (size_t)q0 * 256};

  f32x4 acc[4][2];
#pragma unroll
  for (int mf = 0; mf < 4; ++mf)
#pragma unroll
    for (int nf = 0; nf < 2; ++nf)
      acc[mf][nf] = (f32x4){0.f, 0.f, 0.f, 0.f};

  // stage tile kt into buffer b: 512 chunks/plane, 1 chunk/thread/plane.
  auto stage = [&](int b, int kt) {
    char* base = smem + b * 32768;
    int row = t >> 2, sl = t & 3;
    int q = sl ^ ((row >> 1) & 3);
    size_t goff = (size_t)row * 256 + kt * 32 + (q << 3);
#pragma unroll
    for (int pl = 0; pl < 4; ++pl)
      gl16(srcs[pl] + goff, base + pl * 8192 + t * 16);
  };

  stage(0, 0);
  stage(1, 1);
  asm volatile("s_waitcnt vmcnt(4)" ::: "memory");   // tile 0 landed
  __builtin_amdgcn_sched_barrier(0);
  __builtin_amdgcn_s_barrier();
  __builtin_amdgcn_sched_barrier(0);

#pragma unroll
  for (int kt = 0; kt < 8; ++kt) {
    int b = kt & 1;
    char* sAh = smem + b * 32768;
    char* sAl = sAh + 8192;
    char* sBh = sAh + 16384;
    char* sBl = sAh + 24576;
    bf16x8 ah[4], al[4];
#pragma unroll
    for (int mf = 0; mf < 4; ++mf) {
      int row = wm * 64 + mf * 16 + lr;
      int off = row * 64 + ((lh ^ ((row >> 1) & 3)) << 4);
      ah[mf] = *(const bf16x8*)(sAh + off);
      al[mf] = *(const bf16x8*)(sAl + off);
    }
#pragma unroll
    for (int nf = 0; nf < 2; ++nf) {
      int row = wq4 * 32 + nf * 16 + lr;
      int off = row * 64 + ((lh ^ ((row >> 1) & 3)) << 4);
      bf16x8 bh = *(const bf16x8*)(sBh + off);
      bf16x8 bl = *(const bf16x8*)(sBl + off);
#pragma unroll
      for (int mf = 0; mf < 4; ++mf) {
        acc[mf][nf] = __builtin_amdgcn_mfma_f32_16x16x32_bf16(ah[mf], bh, acc[mf][nf], 0, 0, 0);
        acc[mf][nf] = __builtin_amdgcn_mfma_f32_16x16x32_bf16(al[mf], bh, acc[mf][nf], 0, 0, 0);
        acc[mf][nf] = __builtin_amdgcn_mfma_f32_16x16x32_bf16(ah[mf], bl, acc[mf][nf], 0, 0, 0);
      }
    }
    if (kt == 7) break;
    __builtin_amdgcn_sched_barrier(0);
    __builtin_amdgcn_s_barrier();        // readers of buf b done
    __builtin_amdgcn_sched_barrier(0);
    if (kt < 6) {
      stage(b, kt + 2);
      asm volatile("s_waitcnt vmcnt(4)" ::: "memory");  // tile kt+1 landed
    } else {
      asm volatile("s_waitcnt vmcnt(0)" ::: "memory");  // tile 7 landed
    }
    __builtin_amdgcn_sched_barrier(0);
    __builtin_amdgcn_s_barrier();
    __builtin_amdgcn_sched_barrier(0);
  }
  __syncthreads();   // MFMA(7) reads done before epilogue overwrites smem

  // Q epilogue: 2 passes (q-half). Per pass, 4 waves stage both p-half
  // quadrants into buf0/buf1 [64][68]; 512 threads compute + NT store.
  float* sq = (float*)smem;
#pragma unroll
  for (int pass = 0; pass < 2; ++pass) {
    if (pass) __syncthreads();
    if ((wq4 >> 1) == pass) {
      float* buf = sq + wm * 4352;
      int cbase = (wq4 & 1) * 32;
#pragma unroll
      for (int mf = 0; mf < 4; ++mf)
#pragma unroll
        for (int nf = 0; nf < 2; ++nf)
#pragma unroll
          for (int j = 0; j < 4; ++j)
            buf[(mf * 16 + lh * 4 + j) * 68 + cbase + nf * 16 + lr] = acc[mf][nf][j];
      if ((wq4 & 1) == 0)
        *(f32x4*)(buf + l * 68 + 64) = (f32x4){0.f, 0.f, 0.f, 0.f};
    }
    __syncthreads();
    int sel = t >> 8, rest = t & 255;
    int ax = rest & 63, quarter = rest >> 6;
    int rr1 = ax + 1 > 63 ? 63 : ax + 1;
    int rr2 = ax + 2 > 63 ? 63 : ax + 2;
    const float* S = sq + sel * 4352;
    const float* S0 = S + ax * 68;
    const float* S1 = S + rr1 * 68;
    const float* S2 = S + rr2 * 68;
    int planeIdx = (((p0 >> 6) + sel) << 6) + (q0 >> 6) + pass;
    float* Qp = P + (((size_t)planeIdx) << 12);
#pragma unroll
    for (int gi2 = 0; gi2 < 2; ++gi2) {
      int g = quarter * 2 + gi2;
      int c0 = g * 8;
      float r0[12], r1a[12], r2a[12];
#pragma unroll
      for (int u = 0; u < 3; ++u) {
        *(f32x4*)(r0 + u * 4) = *(const f32x4*)(S0 + c0 + u * 4);
        *(f32x4*)(r1a + u * 4) = *(const f32x4*)(S1 + c0 + u * 4);
        *(f32x4*)(r2a + u * 4) = *(const f32x4*)(S2 + c0 + u * 4);
      }
      f32x4 qv0, qv1;
#pragma unroll
      for (int e = 0; e < 4; ++e) qv0[e] = r0[e] + r1a[e + 1] + r2a[e + 2];
#pragma unroll
      for (int e = 0; e < 4; ++e) qv1[e] = r0[e + 4] + r1a[e + 5] + r2a[e + 6];
      float* Qg = Qp + g * 512 + (ax << 2);
      __builtin_nontemporal_store(qv0, (f32x4*)(Qg));
      __builtin_nontemporal_store(qv1, (f32x4*)(Qg + 256));
    }
  }
}

// ---------------------------------------------------------------------------
// reduce body (512 threads): thread (w2 = t>>6) owns ONE ww group; NT loads,
// 3-deep register-rolling prefetch. Same loads/compares/stores as champion.
// ---------------------------------------------------------------------------
__device__ __forceinline__ void reduce_body(int rid, const char* slot,
                                            float* pval8, u8* pidx8, int t) {
  const float* QT = (const float*)(slot + SP_Q);

  int bid = rid;
  int ki = 0;
  for (ki = 0; ki < 123; ++ki) {
    int d = ki - 61; if (d < 0) d = -d;
    int ns = (62 - d + SEG - 1) / SEG;
    if (bid < ns) break;
    bid -= ns;
  }
  int k = ki - 61;
  int ystart = k < 0 ? -k : 0;
  int yend = k > 0 ? 61 - k : 61;
  int y0 = ystart + bid * SEG;
  int y1 = y0 + SEG; if (y1 > yend + 1) y1 = yend + 1;
  int sid0 = pre_of(ki) + (y0 - ystart);
  int pmax = yend + 2;

  int w2 = t >> 6, l = t & 63;   // w2 0..7

  float A[8], B[8], P0[8], P1[8], P2[8];

  auto ld = [&](int p, float* D) {
    const float* gp = QT + (((size_t)((p << 6) + (p + k))) << 12) + (w2 << 9) + (l << 2);
    *(f32x4*)(D) = __builtin_nontemporal_load((const f32x4*)gp);
    *(f32x4*)(D + 4) = __builtin_nontemporal_load((const f32x4*)(gp + 256));
  };

  auto candstep = [&](int y, const float* D0, const float* D1, const float* D2) {
    float best = __uint_as_float(0xFF800000u);
    int bbb = 0;
#pragma unroll
    for (int s = 0; s < 8; ++s) {
      float c = D0[s] + D1[s] + D2[s];
      bool valid = (w2 * 8 + s) <= 61;
      if (valid && c > best) { best = c; bbb = s; }  // ascending s
    }
    size_t o = (size_t)(sid0 + (y - y0)) * 512 + (w2 << 6) + l;
    pval8[o] = best;
    pidx8[o] = (u8)bbb;
  };

  ld(y0, A);
  ld(y0 + 1, B);
  ld(y0 + 2, P0);
  ld(y0 + 3 > pmax ? pmax : y0 + 3, P1);
  ld(y0 + 4 > pmax ? pmax : y0 + 4, P2);

  int y = y0;
  while (true) {
    candstep(y, A, B, P0);
#pragma unroll
    for (int s = 0; s < 8; ++s) { A[s] = B[s]; B[s] = P0[s]; }
    if (++y >= y1) break;
    ld(y + 4 > pmax ? pmax : y + 4, P0);
    candstep(y, A, B, P1);
#pragma unroll
    for (int s = 0; s < 8; ++s) { A[s] = B[s]; B[s] = P1[s]; }
    if (++y >= y1) break;
    ld(y + 4 > pmax ? pmax : y + 4, P1);
    candstep(y, A, B, P2);
#pragma unroll
    for (int s = 0; s < 8; ++s) { A[s] = B[s]; B[s] = P2[s]; }
    if (++y >= y1) break;
    ld(y + 4 > pmax ? pmax : y + 4, P2);
  }
}

// ---------------------------------------------------------------------------
// standalone convert (prologue C(0)), 512 threads
// ---------------------------------------------------------------------------
__global__ __launch_bounds__(512) void convert_kernel(const float* __restrict__ f1,
                                                      const float* __restrict__ f2,
                                                      const float* __restrict__ rnorm,
                                                      int bi, char* __restrict__ slot) {
  __shared__ __align__(16) char smem[33024];
  convert_body(blockIdx.x, blockIdx.y, bi, f1, f2, rnorm, slot, smem, threadIdx.x);
}

// ---------------------------------------------------------------------------
// merged phase kernel (512 threads, 4 waves/SIMD at 2 blocks/CU):
// role-striped blocks (2:1 pgemm:reduce + convert tail).
// ---------------------------------------------------------------------------
__global__ __launch_bounds__(512, 4) void merged_kernel(const float* __restrict__ f1,
                                                        const float* __restrict__ f2,
                                                        const float* __restrict__ rnorm,
                                                        char* __restrict__ ws,
                                                        int pg_img, int rd_img, int cv_img) {
  __shared__ __align__(16) char smem[65536];
  int bx = blockIdx.x, t = threadIdx.x;
  char* slot0 = ws + OFF_SLOT0;

  if (bx < 1608) {
    int m = bx % 3;
    if (m < 2) {
      int pid = (bx / 3) * 2 + m;
      if (pg_img >= 0 && pid < 1024)
        pgemm_body(pid, slot0 + (size_t)(pg_img & 1) * SLOT_BYTES, smem, t);
    } else {
      int rid = bx / 3;
      if (rd_img >= 0) {
        float* pv = (float*)(ws + OFF_PV) + (size_t)rd_img * PVIMG;
        u8* pi = (u8*)(ws + OFF_PI) + (size_t)rd_img * PVIMG;
        reduce_body(rid, slot0 + (size_t)(rd_img & 1) * SLOT_BYTES, pv, pi, t);
      }
    }
  } else {
    int cid = bx - 1608;
    if (cv_img >= 0)
      convert_body(cid & 127, cid >> 7, cv_img, f1, f2, rnorm,
                   slot0 + (size_t)(cv_img & 1) * SLOT_BYTES, smem, t);
  }
}

// ---------------------------------------------------------------------------
// combine: scan (jy, w) with exact compares; decode bb via one pidx read.
// ---------------------------------------------------------------------------
__global__ __launch_bounds__(256) void combine_kernel(const char* __restrict__ ws,
                                                      float* __restrict__ resv,
                                                      int* __restrict__ residx) {
  int q = blockIdx.x * 256 + threadIdx.x;
  if (q >= NQ) return;
  int b = blockIdx.y;
  const float* pval8 = (const float*)(ws + OFF_PV) + (size_t)b * PVIMG;
  const u8* pidx8 = (const u8*)(ws + OFF_PI) + (size_t)b * PVIMG;
  int y = q / 62, ax = q - y * 62;
  float best = __uint_as_float(0xFF800000u);
  int bjy = 0, bw = 0;
  for (int jy = 0; jy < 62; ++jy) {
    int ki = 61 + jy - y;
    int sid = pre_of(ki) + (y < jy ? y : jy);
    const float* p = pval8 + (size_t)sid * 512 + ax;
#pragma unroll
    for (int ww = 0; ww < 8; ++ww) {
      float v = p[ww << 6];
      if (v > best) { best = v; bjy = jy; bw = ww; }
    }
  }
  int kib = 61 + bjy - y;
  int sidb = pre_of(kib) + (y < bjy ? y : bjy);
  int bb = pidx8[(size_t)sidb * 512 + (bw << 6) + ax];
  resv[(size_t)b * NQ + q] = best;
  residx[(size_t)b * NQ + q] = bjy * 62 + bw * 8 + bb;
}

// ---------------------------------------------------------------------------
// assemble: flow (B,64,64,2), offset (B,9,64,64,2), sim (B,1,64,64)
// ---------------------------------------------------------------------------
__global__ __launch_bounds__(256) void assemble_kernel(const float* __restrict__ res_val,
                                                       const int* __restrict__ res_idx,
                                                       float* __restrict__ out) {
  int gid = blockIdx.x * 256 + threadIdx.x;
  if (gid >= BATCH * HW) return;
  int b = gid >> 12;
  int y = (gid >> 6) & 63;
  int x = gid & 63;

  float* out_flow = out;
  float* out_off = out + (size_t)BATCH * HW * 2;
  float* out_sim = out + (size_t)BATCH * HW * 2 + (size_t)BATCH * 9 * HW * 2;

  auto flow_at = [&](int yy, int xx, float* fx, float* fy) {
    if (yy >= 0 && yy < HH && xx >= 0 && xx < WW) {
      int idx = res_idx[(size_t)b * NQ + yy * WW + xx];
      *fx = (float)(idx % WW - xx);
      *fy = (float)(idx / WW - yy);
    } else {
      *fx = 0.f;
      *fy = 0.f;
    }
  };

  float fx, fy;
  flow_at(y, x, &fx, &fy);
  size_t fo = ((size_t)b * HW + y * W + x) * 2;
  out_flow[fo + 0] = fx;
  out_flow[fo + 1] = fy;

#pragma unroll
  for (int sft = 0; sft < 9; ++sft) {
    int i = sft / 3, jj = sft % 3;
    float ox, oy;
    flow_at(y - i, x - jj, &ox, &oy);
    size_t o = (((size_t)b * 9 + sft) * HW + y * W + x) * 2;
    out_off[o + 0] = ox;
    out_off[o + 1] = oy;
  }

  float sim = 0.f;
  if (y >= 1 && y <= HH && x >= 1 && x <= WW) {
    float mv = res_val[(size_t)b * NQ + (y - 1) * WW + (x - 1)];
    sim = mv * (1.0f / ((3.0f + 1e-5f) * 3.0f));  // patch norms are exactly 3
  }
  out_sim[(size_t)b * HW + y * W + x] = sim;
}

// ---------------------------------------------------------------------------
extern "C" void kernel_launch(void* const* d_in, const int* in_sizes, int n_in,
                              void* d_out, int out_size, void* d_ws, size_t ws_size,
                              hipStream_t stream) {
  const float* f1 = (const float*)d_in[0];
  const float* f2 = (const float*)d_in[1];
  float* out = (float*)d_out;
  char* ws = (char*)d_ws;

  float* rnorm = (float*)(ws + OFF_RNORM);
  float* resv = (float*)(ws + OFF_RESV);
  int* residx = (int*)(ws + OFF_RESI);
  char* slot0 = ws + OFF_SLOT0;

  norm_kernel<<<dim3(BATCH * H, 2), 256, 0, stream>>>(f1, f2, rnorm);
  convert_kernel<<<dim3(128, 2), 512, 0, stream>>>(f1, f2, rnorm, 0, slot0);

  for (int i = 0; i < 8; ++i) {
    int cv = (i + 1 < 8) ? i + 1 : -1;
    merged_kernel<<<1864, 512, 0, stream>>>(f1, f2, rnorm, ws, i, i - 1, cv);
  }
  merged_kernel<<<1864, 512, 0, stream>>>(f1, f2, rnorm, ws, -1, 7, -1);

  combine_kernel<<<dim3(16, BATCH), 256, 0, stream>>>(ws, resv, residx);

  int total = BATCH * HW;
  assemble_kernel<<<(total + 255) / 256, 256, 0, stream>>>(resv, residx, out);
}